// Round 1
// baseline (400.983 us; speedup 1.0000x reference)
//
#include <hip/hip_runtime.h>
#include <math.h>

// Min-sum BP LDPC decoder, LDS-resident messages, degree-sorted checks.
// One block = one batch element; msg[] (E=32768 floats = 128 KB) lives in LDS
// for all 10 iterations. Edges are contiguous per check (np.nonzero order).
//
// R2 changes vs R1:
//  - XOR bank swizzle on ALL msg[] accesses: f(e) = e ^ ((e>>5)&31).
//    Check phase reads msg[st + l*d + j] across lanes (d~8 after degree sort)
//    = 16-way bank conflict (4 distinct banks for 64 lanes). Swizzle spreads
//    to ~2-way (free). Var-phase addresses pre-swizzled into registers once.
//  - min1/min2 via v_min + v_med3 identity (min2' = med3(min1, min2, a)),
//    ALPHA folded per-check, clamp via v_med3(x, -20, 20), parity as ±1.0f
//    product (cndmask w/ neg modifier). Tie rule stays reference-exact:
//    |a - min1| < 1e-9 (NOT a < min1+1e-9, which rounds away at fp32).

#define BLOCK 1024
#define NV    8192          // N variables
#define MC    4096          // M checks
#define NE    32768         // E edges (N * DV, DV=4)
#define VPT   (NV / BLOCK)  // 8 vars per thread
#define CPT   (MC / BLOCK)  // 4 checks per thread
#define NITER 10
#define ALPHA 0.8f
#define CLAMP 20.0f

// bank swizzle: bijective (upper bits unchanged, low 5 XORed with bits 5..9)
__device__ __forceinline__ int swz(int e) { return e ^ ((e >> 5) & 31); }

// ---------------- setup: counting-sort checks by degree ----------------
// ws[0..MC)    : (cstart & 0xFFFF) | (deg << 16), degree-sorted
// ws[MC..2MC)  : original check index (for syndrome lookup), same order
__global__ __launch_bounds__(BLOCK)
void setup_sort(const float* __restrict__ check_mask,
                const int*   __restrict__ check_adj,
                int max_dc, int* __restrict__ ws)
{
    __shared__ int hist[64];
    __shared__ int base[64];
    const int t = threadIdx.x;
    if (t < 64) hist[t] = 0;
    __syncthreads();
    int deg[CPT], cst[CPT];
#pragma unroll
    for (int k = 0; k < CPT; ++k) {
        const int c = t + k * BLOCK;
        int d = 0;
        for (int j = 0; j < max_dc; ++j)
            d += (check_mask[(size_t)c * max_dc + j] != 0.0f) ? 1 : 0;
        deg[k] = d;
        cst[k] = check_adj[(size_t)c * max_dc];  // row start (edges sorted by check)
        atomicAdd(&hist[d & 63], 1);
    }
    __syncthreads();
    if (t == 0) {
        int s = 0;
        for (int i = 0; i < 64; ++i) { base[i] = s; s += hist[i]; }
    }
    __syncthreads();
#pragma unroll
    for (int k = 0; k < CPT; ++k) {
        const int c   = t + k * BLOCK;
        const int pos = atomicAdd(&base[deg[k] & 63], 1);
        ws[pos]      = (cst[k] & 0xFFFF) | (deg[k] << 16);
        ws[MC + pos] = c;
    }
}

// Single-pass check update with register-cached edge values + swizzled addrs.
// DMAX is a compile-time cap; loops fully unrolled so x[]/ad[] stay in VGPRs.
template<int DMAX, bool CACHE_ADDR>
__device__ __forceinline__ void do_check(float* __restrict__ msg,
                                         int st, int d, float sgn, float pad)
{
    float x[DMAX];
    int   ad[CACHE_ADDR ? DMAX : 1];
    float min1 = pad, min2 = pad;
    float prod = sgn;                      // syndrome sign, flipped per neg edge
#pragma unroll
    for (int j = 0; j < DMAX; ++j) {
        if (j >= d) break;
        const int a = swz(st + j);
        if (CACHE_ADDR) ad[j] = a;
        x[j] = msg[a];
    }
#pragma unroll
    for (int j = 0; j < DMAX; ++j) {
        if (j >= d) break;
        prod = (x[j] < 0.0f) ? -prod : prod;   // sign(-0)=+1 like reference
        const float a = fabsf(x[j]);
        min2 = __builtin_amdgcn_fmed3f(min1, min2, a);  // uses OLD min1
        min1 = fminf(min1, a);
    }
    const float vm1 = ALPHA * min1;
    const float vm2 = ALPHA * min2;
#pragma unroll
    for (int j = 0; j < DMAX; ++j) {
        if (j >= d) break;
        const float m = (fabsf(fabsf(x[j]) - min1) < 1e-9f) ? vm2 : vm1;
        const float s = (x[j] < 0.0f) ? -prod : prod;   // excl_sign
        const int  a = CACHE_ADDR ? ad[j] : swz(st + j);
        msg[a] = m * s;
    }
}

// Generic fallback for d > 16 (rare; re-reads LDS instead of caching).
__device__ __forceinline__ void do_check_big(float* __restrict__ msg,
                                             int st, int d, float sgn, float pad)
{
    float min1 = pad, min2 = pad;
    float prod = sgn;
    for (int j = 0; j < d; ++j) {
        const float xx = msg[swz(st + j)];
        prod = (xx < 0.0f) ? -prod : prod;
        const float a = fabsf(xx);
        min2 = __builtin_amdgcn_fmed3f(min1, min2, a);
        min1 = fminf(min1, a);
    }
    const float vm1 = ALPHA * min1;
    const float vm2 = ALPHA * min2;
    for (int j = 0; j < d; ++j) {
        const int   a  = swz(st + j);
        const float xx = msg[a];
        const float m  = (fabsf(fabsf(xx) - min1) < 1e-9f) ? vm2 : vm1;
        const float s  = (xx < 0.0f) ? -prod : prod;
        msg[a] = m * s;
    }
}

__global__ __launch_bounds__(BLOCK)
void bp_decode(const float* __restrict__ syndrome,    // (B, M)
               const float* __restrict__ llr_g,       // (B, N)
               const int*   __restrict__ var_adj,     // (N, 4)
               const int*   __restrict__ ws,          // sorted check info
               float* __restrict__ out,               // marginals | hard | converged
               int B)
{
    __shared__ float msg[NE];   // 128 KB: ctv, then vtc in-place (SWIZZLED layout)
    __shared__ float sh_e0;     // |vtc[edge 0]| snapshot for reference's pad
    __shared__ int   mism;

    const int b = blockIdx.x;
    const int t = threadIdx.x;

    for (int e = t; e < NE; e += BLOCK) msg[e] = 0.0f;   // ctv0 = 0 (order-free)

    // ---- preload per-thread read-only data into registers ----
    int   vs[VPT][4];            // swizzled edge indices for this thread's vars
    float llr[VPT];
    bool  e0own = false;
#pragma unroll
    for (int k = 0; k < VPT; ++k) {
        const int v = t + k * BLOCK;
        const int4 a = ((const int4*)var_adj)[v];   // var degree is exactly 4
        e0own |= (a.x == 0) | (a.y == 0) | (a.z == 0) | (a.w == 0);
        vs[k][0] = swz(a.x); vs[k][1] = swz(a.y);
        vs[k][2] = swz(a.z); vs[k][3] = swz(a.w);
        llr[k] = llr_g[(size_t)b * NV + v];
    }
    int cst[CPT], dsb[CPT];   // dsb = (deg<<1) | syndrome_bit
#pragma unroll
    for (int k = 0; k < CPT; ++k) {
        const int i = t + k * BLOCK;
        const int w = ws[i];
        const int c = ws[MC + i];
        cst[k] = w & 0xFFFF;
        const int d  = w >> 16;
        const int sb = (syndrome[(size_t)b * MC + c] > 0.5f) ? 1 : 0;
        dsb[k] = (d << 1) | sb;
    }
    __syncthreads();

    for (int it = 0; it < NITER; ++it) {
        // ---- variable phase: msg(ctv) -> msg(vtc), in place ----
#pragma unroll
        for (int k = 0; k < VPT; ++k) {
            const float c0 = msg[vs[k][0]];
            const float c1 = msg[vs[k][1]];
            const float c2 = msg[vs[k][2]];
            const float c3 = msg[vs[k][3]];
            const float tot  = ((c0 + c1) + c2) + c3;   // reference sum order
            const float base = llr[k] + tot;
            msg[vs[k][0]] = __builtin_amdgcn_fmed3f(base - c0, -CLAMP, CLAMP);
            msg[vs[k][1]] = __builtin_amdgcn_fmed3f(base - c1, -CLAMP, CLAMP);
            msg[vs[k][2]] = __builtin_amdgcn_fmed3f(base - c2, -CLAMP, CLAMP);
            msg[vs[k][3]] = __builtin_amdgcn_fmed3f(base - c3, -CLAMP, CLAMP);
        }
        // Reference pads short checks with edge 0's value: |vtc[0]| + 1e6.
        // Edge 0's owner just wrote msg[swz(0)] = msg[0]; publish pre-barrier.
        if (e0own) sh_e0 = fabsf(msg[0]) + 1.0e6f;
        __syncthreads();
        const float pad = sh_e0;

        // ---- check phase: msg(vtc) -> msg(ctv_new), in place ----
#pragma unroll
        for (int k = 0; k < CPT; ++k) {
            const int d  = dsb[k] >> 1;
            const float sgn = (dsb[k] & 1) ? -1.0f : 1.0f;
            const int st = cst[k];
            if (d <= 8)       do_check<8,  true >(msg, st, d, sgn, pad);
            else if (d <= 12) do_check<12, true >(msg, st, d, sgn, pad);
            else if (d <= 16) do_check<16, false>(msg, st, d, sgn, pad);
            else              do_check_big(msg, st, d, sgn, pad);
        }
        __syncthreads();
    }

    // ---- finale: marginals, hard decisions, convergence ----
    float marg[VPT], hard[VPT];
#pragma unroll
    for (int k = 0; k < VPT; ++k) {
        const float c0 = msg[vs[k][0]];
        const float c1 = msg[vs[k][1]];
        const float c2 = msg[vs[k][2]];
        const float c3 = msg[vs[k][3]];
        const float tot = ((c0 + c1) + c2) + c3;
        const float tl  = llr[k] + tot;
        const float mg  = 1.0f / (1.0f + expf(tl));   // sigmoid(-tl)
        marg[k] = mg;
        hard[k] = (mg > 0.5f) ? 1.0f : 0.0f;
    }
    if (t == 0) mism = 0;
    __syncthreads();   // all ctv reads done; safe to overwrite msg

    const size_t BN = (size_t)B * NV;
#pragma unroll
    for (int k = 0; k < VPT; ++k) {
        const int v = t + k * BLOCK;
        out[(size_t)b * NV + v]      = marg[k];        // output 0: marginals
        out[BN + (size_t)b * NV + v] = hard[k];        // output 1: hard_decision
        const float h = hard[k];                       // scatter hard bit to edges
        msg[vs[k][0]] = h;
        msg[vs[k][1]] = h;
        msg[vs[k][2]] = h;
        msg[vs[k][3]] = h;
    }
    __syncthreads();

    // syn_hat[c] = parity over the check's edges' hard bits; converged iff == syndrome
#pragma unroll
    for (int k = 0; k < CPT; ++k) {
        const int d  = dsb[k] >> 1;
        const int sb = dsb[k] & 1;
        const int st = cst[k];
        int par = 0;
        for (int j = 0; j < d; ++j)
            par ^= (msg[swz(st + j)] != 0.0f) ? 1 : 0;
        if (par != sb) mism = 1;   // benign race: all writers store 1
    }
    __syncthreads();
    if (t == 0) out[2 * BN + b] = mism ? 0.0f : 1.0f;  // output 2: converged
}

extern "C" void kernel_launch(void* const* d_in, const int* in_sizes, int n_in,
                              void* d_out, int out_size, void* d_ws, size_t ws_size,
                              hipStream_t stream) {
    const float* syndrome   = (const float*)d_in[0];
    const float* llr        = (const float*)d_in[1];
    const int*   var_adj    = (const int*)d_in[2];
    // d_in[3] var_adj_mask: all ones (DV=4 exact) — unused
    const int*   check_adj  = (const int*)d_in[4];
    const float* check_mask = (const float*)d_in[5];
    // d_in[6] var_idx — unused (parity via hard-bit scatter)
    // d_in[7] pcm_dense — unused
    float* out = (float*)d_out;
    int*   ws  = (int*)d_ws;    // needs 2*MC ints = 32 KB

    const int B      = in_sizes[0] / MC;      // 256
    const int max_dc = in_sizes[4] / MC;

    setup_sort<<<1, BLOCK, 0, stream>>>(check_mask, check_adj, max_dc, ws);
    bp_decode<<<B, BLOCK, 0, stream>>>(syndrome, llr, var_adj, ws, out, B);
}